// Round 3
// baseline (362.799 us; speedup 1.0000x reference)
//
#include <hip/hip_runtime.h>
#include <stdint.h>

#define TOKENS 8192
#define INF    4096
#define OUTF   4096
#define RANK   256

typedef __attribute__((ext_vector_type(8))) short bf16x8;
typedef __attribute__((ext_vector_type(4))) float f32x4;

__device__ __forceinline__ unsigned short f2bf(float f) {
    union { float f; unsigned int u; } v; v.f = f;
    unsigned int r = v.u + 0x7FFFu + ((v.u >> 16) & 1u);   // RNE
    return (unsigned short)(r >> 16);
}

__device__ __forceinline__ void gl_lds16(const void* g, void* l) {
    __builtin_amdgcn_global_load_lds(
        (const __attribute__((address_space(1))) unsigned int*)g,
        (__attribute__((address_space(3))) unsigned int*)l, 16, 0, 0);
}

// ---------------- fp32 -> bf16 convert ----------------
__global__ void cvt4(const float4* __restrict__ in, ushort4* __restrict__ out) {
    int i = blockIdx.x * blockDim.x + threadIdx.x;
    float4 v = in[i];
    ushort4 o;
    o.x = f2bf(v.x); o.y = f2bf(v.y); o.z = f2bf(v.z); o.w = f2bf(v.w);
    out[i] = o;
}

// ============ GEMM1 split-K: T32[8192,256] += x @ V^T (fp32 atomic) =======
// BM=32 tokens, BN=256 (full rank -> x read ONCE), BK=64, KSPLIT=4.
// grid (4, 256) = 1024 blocks, 512 thr (8 waves) => ~3 blocks/CU resident.
#define G1_BM  32
#define G1_BK  64
#define KSPLIT 4
#define KSEG   (INF / KSPLIT)   // 1024
#define A1_STR 72               // padded bf16 elems/row for x-tile

__global__ __launch_bounds__(512) void gemm1_sk(const float* __restrict__ x,
                                                const unsigned short* __restrict__ Vb,
                                                float* __restrict__ T32) {
    __shared__ __align__(16) unsigned short Bvlds[RANK * G1_BK];     // 32 KB
    __shared__ __align__(16) unsigned short Axlds[G1_BM * A1_STR];   // 4.6 KB

    const int tid   = threadIdx.x;
    const int lane  = tid & 63;
    const int wid   = tid >> 6;            // 0..7
    const int m0    = blockIdx.y * G1_BM;  // token base
    const int kbase = blockIdx.x * KSEG;   // k range base
    const int l15   = lane & 15;
    const int quad  = lane >> 4;

    // V staging: per instr 8 rows x 8 chunks, XOR-swizzled chunk
    const int lrow = lane >> 3;            // 0..7
    const int cf   = (lane & 7) ^ lrow;    // fetched chunk for this lane

    // x staging: thread -> (row 0..31, 4-elem k segment 0..15)
    const int arow = tid >> 4;
    const int aseg = tid & 15;
    const float* xa = x + (size_t)(m0 + arow) * INF + kbase + aseg * 4;
    unsigned short* alds_w = &Axlds[arow * A1_STR + aseg * 4];

    f32x4 acc[2][2];
    #pragma unroll
    for (int i = 0; i < 2; i++)
        #pragma unroll
        for (int j = 0; j < 2; j++) acc[i][j] = (f32x4){0.f, 0.f, 0.f, 0.f};

    for (int kk = 0; kk < KSEG; kk += G1_BK) {
        // stage V (bf16) async: 8 waves x 4 instrs x 8 rows = 256 rows
        #pragma unroll
        for (int j = 0; j < 4; ++j) {
            int r0 = wid * 32 + j * 8;
            gl_lds16(Vb + (size_t)(r0 + lrow) * INF + kbase + kk + cf * 8,
                     &Bvlds[r0 * G1_BK]);
        }
        // stage x (fp32 -> bf16): 1 float4 load + pack + ds_write_b64
        float4 v = *(const float4*)(xa + kk);
        {
            ushort4 pk;
            pk.x = f2bf(v.x); pk.y = f2bf(v.y);
            pk.z = f2bf(v.z); pk.w = f2bf(v.w);
            *(ushort4*)alds_w = pk;
        }
        __syncthreads();
        #pragma unroll
        for (int ks = 0; ks < 2; ++ks) {
            bf16x8 aV[2], bx[2];
            #pragma unroll
            for (int nt = 0; nt < 2; ++nt) {
                int rr = wid * 32 + nt * 16 + l15;
                int p  = (ks * 4 + quad) ^ (rr & 7);
                aV[nt] = *(const bf16x8*)&Bvlds[rr * G1_BK + p * 8];
            }
            #pragma unroll
            for (int mt = 0; mt < 2; ++mt) {
                int tr = mt * 16 + l15;
                bx[mt] = *(const bf16x8*)&Axlds[tr * A1_STR + ks * 32 + quad * 8];
            }
            #pragma unroll
            for (int mt = 0; mt < 2; ++mt)
                #pragma unroll
                for (int nt = 0; nt < 2; ++nt)
                    acc[mt][nt] = __builtin_amdgcn_mfma_f32_16x16x32_bf16(
                        aV[nt], bx[mt], acc[mt][nt], 0, 0, 0);
        }
        __syncthreads();
    }
    // epilogue: D col = token (l15), row = rank (quad*4+r) -> fp32 atomics
    #pragma unroll
    for (int mt = 0; mt < 2; ++mt) {
        int m = m0 + mt * 16 + l15;
        #pragma unroll
        for (int nt = 0; nt < 2; ++nt) {
            int nb = wid * 32 + nt * 16 + quad * 4;
            #pragma unroll
            for (int r = 0; r < 4; ++r)
                atomicAdd(&T32[(size_t)m * RANK + nb + r], acc[mt][nt][r]);
        }
    }
}

// ============ GEMM1 fallback (no split-K; proven R2 path) =================
#define F1_BM 32
#define F1_BN 128
#define F1_BK 128
#define F1_STR 136

__global__ __launch_bounds__(512) void gemm1_ns(const float* __restrict__ x,
                                                const unsigned short* __restrict__ Vb,
                                                unsigned short* __restrict__ T) {
    __shared__ __align__(16) unsigned short Axlds[F1_BM * F1_STR];
    __shared__ __align__(16) unsigned short Bvlds[F1_BN * F1_BK];

    const int tid  = threadIdx.x;
    const int lane = tid & 63;
    const int wid  = tid >> 6;
    const int m0   = blockIdx.y * F1_BM;
    const int n0   = blockIdx.x * F1_BN;
    const int l15  = lane & 15;
    const int quad = lane >> 4;

    const int arow = tid >> 4;
    const int aseg = tid & 15;
    const float* xa = x + (size_t)(m0 + arow) * INF + aseg * 8;
    unsigned short* alds_w = &Axlds[arow * F1_STR + aseg * 8];

    const int b_lrow = lane >> 4;
    const int b_pos  = lane & 15;

    f32x4 acc[2];
    acc[0] = (f32x4){0.f, 0.f, 0.f, 0.f};
    acc[1] = (f32x4){0.f, 0.f, 0.f, 0.f};

    for (int kk = 0; kk < INF; kk += F1_BK) {
        #pragma unroll
        for (int j = 0; j < 4; ++j) {
            int r0  = j * 32 + wid * 4;
            int row = r0 + b_lrow;
            int cfx = b_pos ^ (row & 7);
            gl_lds16(Vb + (size_t)(n0 + row) * INF + kk + cfx * 8,
                     &Bvlds[r0 * F1_BK]);
        }
        float4 va = *(const float4*)(xa + kk);
        float4 vb = *(const float4*)(xa + kk + 4);
        {
            union { bf16x8 v; unsigned short s[8]; } pk;
            pk.s[0] = f2bf(va.x); pk.s[1] = f2bf(va.y);
            pk.s[2] = f2bf(va.z); pk.s[3] = f2bf(va.w);
            pk.s[4] = f2bf(vb.x); pk.s[5] = f2bf(vb.y);
            pk.s[6] = f2bf(vb.z); pk.s[7] = f2bf(vb.w);
            *(bf16x8*)alds_w = pk.v;
        }
        __syncthreads();
        #pragma unroll
        for (int ks = 0; ks < 4; ++ks) {
            int rr = wid * 16 + l15;
            int p  = (ks * 4 + quad) ^ (rr & 7);
            bf16x8 aV = *(const bf16x8*)&Bvlds[rr * F1_BK + p * 8];
            #pragma unroll
            for (int mt = 0; mt < 2; ++mt) {
                int tr = mt * 16 + l15;
                bf16x8 bx = *(const bf16x8*)&Axlds[tr * F1_STR + ks * 32 + quad * 8];
                acc[mt] = __builtin_amdgcn_mfma_f32_16x16x32_bf16(aV, bx, acc[mt], 0, 0, 0);
            }
        }
        __syncthreads();
    }
    #pragma unroll
    for (int mt = 0; mt < 2; ++mt) {
        int m      = m0 + mt * 16 + l15;
        int n_base = n0 + wid * 16 + quad * 4;
        ushort4 o;
        o.x = f2bf(acc[mt][0]); o.y = f2bf(acc[mt][1]);
        o.z = f2bf(acc[mt][2]); o.w = f2bf(acc[mt][3]);
        *(ushort4*)&T[(size_t)m * RANK + n_base] = o;
    }
}

// ---------------- GEMM2: out = T @ U^T + bias (bf16 MFMA, fp32 out) -------
#define G2_BM 128
#define G2_BN 128
#define G2_BK 64

__global__ __launch_bounds__(256) void gemm2(const unsigned short* __restrict__ Tb,
                                             const unsigned short* __restrict__ Ub,
                                             const float* __restrict__ bias,
                                             float* __restrict__ out) {
    __shared__ __align__(16) unsigned short Tlds[G2_BM * G2_BK]; // 16 KB
    __shared__ __align__(16) unsigned short Ulds[G2_BN * G2_BK]; // 16 KB

    const int tid  = threadIdx.x;
    const int lane = tid & 63;
    const int wid  = tid >> 6;
    const int wy   = wid >> 1, wx = wid & 1;
    const int m0   = blockIdx.y * G2_BM;
    const int n0   = blockIdx.x * G2_BN;
    const int l15  = lane & 15, quad = lane >> 4;
    const int lrow = lane >> 3;
    const int cf   = (lane & 7) ^ lrow;

    f32x4 acc[4][4];   // [nt][mt]
    #pragma unroll
    for (int i = 0; i < 4; i++)
        #pragma unroll
        for (int j = 0; j < 4; j++) acc[i][j] = (f32x4){0.f, 0.f, 0.f, 0.f};

    for (int kk = 0; kk < RANK; kk += G2_BK) {
        #pragma unroll
        for (int j = 0; j < 4; ++j) {
            int r0 = wid * 32 + j * 8;
            gl_lds16(Tb + (size_t)(m0 + r0 + lrow) * RANK + kk + cf * 8,
                     &Tlds[r0 * G2_BK]);
            gl_lds16(Ub + (size_t)(n0 + r0 + lrow) * RANK + kk + cf * 8,
                     &Ulds[r0 * G2_BK]);
        }
        __syncthreads();
        #pragma unroll
        for (int ks = 0; ks < 2; ++ks) {
            bf16x8 aU[4], bT[4];
            #pragma unroll
            for (int t = 0; t < 4; ++t) {
                int ur = wx * 64 + t * 16 + l15;
                int up = (ks * 4 + quad) ^ (ur & 7);
                aU[t] = *(const bf16x8*)&Ulds[ur * G2_BK + up * 8];
                int tr = wy * 64 + t * 16 + l15;
                int tp = (ks * 4 + quad) ^ (tr & 7);
                bT[t] = *(const bf16x8*)&Tlds[tr * G2_BK + tp * 8];
            }
            #pragma unroll
            for (int nt = 0; nt < 4; ++nt)
                #pragma unroll
                for (int mt = 0; mt < 4; ++mt)
                    acc[nt][mt] = __builtin_amdgcn_mfma_f32_16x16x32_bf16(
                        aU[nt], bT[mt], acc[nt][mt], 0, 0, 0);
        }
        __syncthreads();
    }
    float4 bv[4];
    #pragma unroll
    for (int nt = 0; nt < 4; ++nt)
        bv[nt] = *(const float4*)&bias[n0 + wx * 64 + nt * 16 + quad * 4];
    #pragma unroll
    for (int nt = 0; nt < 4; ++nt) {
        int n_base = n0 + wx * 64 + nt * 16 + quad * 4;
        #pragma unroll
        for (int mt = 0; mt < 4; ++mt) {
            int m = m0 + wy * 64 + mt * 16 + l15;
            float4 v;
            v.x = acc[nt][mt][0] + bv[nt].x;
            v.y = acc[nt][mt][1] + bv[nt].y;
            v.z = acc[nt][mt][2] + bv[nt].z;
            v.w = acc[nt][mt][3] + bv[nt].w;
            *(float4*)&out[(size_t)m * OUTF + n_base] = v;
        }
    }
}

extern "C" void kernel_launch(void* const* d_in, const int* in_sizes, int n_in,
                              void* d_out, int out_size, void* d_ws, size_t ws_size,
                              hipStream_t stream) {
    const float* x    = (const float*)d_in[0];
    const float* U    = (const float*)d_in[1];
    const float* V    = (const float*)d_in[2];
    const float* bias = (const float*)d_in[3];
    float* out = (float*)d_out;

    // ws layout: Vb 2MB | Ub 2MB | Tb 4MB | T32 8MB  => 16 MB
    unsigned short* Vb  = (unsigned short*)d_ws;
    unsigned short* Ub  = Vb + (size_t)RANK * INF;
    unsigned short* Tb  = Ub + (size_t)OUTF * RANK;
    float*          T32 = (float*)(Tb + (size_t)TOKENS * RANK);

    cvt4<<<(RANK * INF / 4) / 256, 256, 0, stream>>>((const float4*)V, (ushort4*)Vb);
    cvt4<<<(OUTF * RANK / 4) / 256, 256, 0, stream>>>((const float4*)U, (ushort4*)Ub);

    const size_t need = (size_t)16 * 1024 * 1024;
    if (ws_size >= need) {
        hipMemsetAsync(T32, 0, (size_t)TOKENS * RANK * sizeof(float), stream);
        gemm1_sk<<<dim3(KSPLIT, TOKENS / G1_BM), 512, 0, stream>>>(x, Vb, T32);
        cvt4<<<(TOKENS * RANK / 4) / 256, 256, 0, stream>>>((const float4*)T32, (ushort4*)Tb);
    } else {
        gemm1_ns<<<dim3(RANK / F1_BN, TOKENS / F1_BM), 512, 0, stream>>>(x, Vb, Tb);
    }
    gemm2<<<dim3(OUTF / G2_BN, TOKENS / G2_BM), 256, 0, stream>>>(Tb, Ub, bias, out);
}

// Round 4
// 361.979 us; speedup vs baseline: 1.0023x; 1.0023x over previous
//
#include <hip/hip_runtime.h>
#include <stdint.h>

#define TOKENS 8192
#define INF    4096
#define OUTF   4096
#define RANK   256

typedef __attribute__((ext_vector_type(8))) short bf16x8;
typedef __attribute__((ext_vector_type(4))) float f32x4;

__device__ __forceinline__ unsigned short f2bf(float f) {
    union { float f; unsigned int u; } v; v.f = f;
    unsigned int r = v.u + 0x7FFFu + ((v.u >> 16) & 1u);   // RNE
    return (unsigned short)(r >> 16);
}

// ---------------- fp32 -> bf16 convert (V, U) ----------------
__global__ void cvt4(const float4* __restrict__ in, ushort4* __restrict__ out) {
    int i = blockIdx.x * blockDim.x + threadIdx.x;
    float4 v = in[i];
    ushort4 o;
    o.x = f2bf(v.x); o.y = f2bf(v.y); o.z = f2bf(v.z); o.w = f2bf(v.w);
    out[i] = o;
}

// ================== Fused: out[32tok x 4096] per block ====================
// grid = 256 (1 block/CU), 512 thr (8 waves).
// Phase 1: T = x @ V^T  (x via LDS; V direct from L2 into A-frags)
// Phase 2: out = T @ U^T + bias (T in LDS B-frag layout; U direct from L2)
#define BM   32
#define BK   128
#define XSTR 136   // padded bf16 elems/row for x tile

__global__ __launch_bounds__(512, 2) void fused(const float* __restrict__ x,
                                                const unsigned short* __restrict__ Vb,
                                                const unsigned short* __restrict__ Ub,
                                                const float* __restrict__ bias,
                                                float* __restrict__ out) {
    __shared__ __align__(16) unsigned short Xlds[BM * XSTR];          // 8.7 KB
    __shared__ __align__(16) unsigned short T2[2 * 8 * 4 * 16 * 8];   // 16 KB

    const int tid  = threadIdx.x;
    const int lane = tid & 63;
    const int wid  = tid >> 6;          // 0..7
    const int l15  = lane & 15;
    const int quad = lane >> 4;
    const int m0   = blockIdx.x * BM;   // token base

    // ---------------- Phase 1 ----------------
    // x staging: thread -> (row 0..31, 8-elem k segment 0..15)
    const int arow = tid >> 4;
    const int aseg = tid & 15;
    const float* xa = x + (size_t)(m0 + arow) * INF + aseg * 8;
    unsigned short* xw = &Xlds[arow * XSTR + aseg * 8];

    f32x4 acc[2][2];   // [rt rank-tile][tt token-tile]
    #pragma unroll
    for (int i = 0; i < 2; i++)
        #pragma unroll
        for (int j = 0; j < 2; j++) acc[i][j] = (f32x4){0.f, 0.f, 0.f, 0.f};

    // register prefetch of x(0)
    float4 ra = *(const float4*)(xa);
    float4 rb = *(const float4*)(xa + 4);

    for (int kk = 0; kk < INF; kk += BK) {
        __syncthreads();   // previous iter's Xlds reads done
        {
            union { bf16x8 v; unsigned short s[8]; } pk;
            pk.s[0] = f2bf(ra.x); pk.s[1] = f2bf(ra.y);
            pk.s[2] = f2bf(ra.z); pk.s[3] = f2bf(ra.w);
            pk.s[4] = f2bf(rb.x); pk.s[5] = f2bf(rb.y);
            pk.s[6] = f2bf(rb.z); pk.s[7] = f2bf(rb.w);
            *(bf16x8*)xw = pk.v;
        }
        if (kk + BK < INF) {           // prefetch x(kk+1); stays in flight
            ra = *(const float4*)(xa + kk + BK);
            rb = *(const float4*)(xa + kk + BK + 4);
        }
        __syncthreads();   // Xlds ready (lgkm only; no LDS-DMA drain)

        #pragma unroll
        for (int ks = 0; ks < 4; ++ks) {
            bf16x8 aV[2], bx[2];
            #pragma unroll
            for (int rt = 0; rt < 2; ++rt) {
                int rr = wid * 32 + rt * 16 + l15;   // rank row
                aV[rt] = *(const bf16x8*)&Vb[(size_t)rr * INF + kk + ks * 32 + quad * 8];
            }
            #pragma unroll
            for (int tt = 0; tt < 2; ++tt) {
                int tr = tt * 16 + l15;              // token row
                bx[tt] = *(const bf16x8*)&Xlds[tr * XSTR + ks * 32 + quad * 8];
            }
            #pragma unroll
            for (int rt = 0; rt < 2; ++rt)
                #pragma unroll
                for (int tt = 0; tt < 2; ++tt)
                    acc[rt][tt] = __builtin_amdgcn_mfma_f32_16x16x32_bf16(
                        aV[rt], bx[tt], acc[rt][tt], 0, 0, 0);
        }
    }

    // Write T into LDS in phase-2 B-frag order:
    // elem (token t = tt*16+l15, rank n = wid*32+rt*16+quad*4+r)
    //   -> T2[(((tt*8 + (n>>5))*4 + ((n>>3)&3))*16 + t15)*8 + (n&7)]
    __syncthreads();
    #pragma unroll
    for (int rt = 0; rt < 2; ++rt)
        #pragma unroll
        for (int tt = 0; tt < 2; ++tt) {
            int quad2 = rt * 2 + (quad >> 1);
            int j0    = (quad & 1) * 4;
            ushort4 o;
            o.x = f2bf(acc[rt][tt][0]); o.y = f2bf(acc[rt][tt][1]);
            o.z = f2bf(acc[rt][tt][2]); o.w = f2bf(acc[rt][tt][3]);
            *(ushort4*)&T2[(((tt * 8 + wid) * 4 + quad2) * 16 + l15) * 8 + j0] = o;
        }
    __syncthreads();

    // ---------------- Phase 2 ----------------
    // B-frags (T) once into regs: lane reads T2[tt][ks][quad][l15][0..7]
    bf16x8 bT[2][8];
    #pragma unroll
    for (int tt = 0; tt < 2; ++tt)
        #pragma unroll
        for (int ks = 0; ks < 8; ++ks)
            bT[tt][ks] = *(const bf16x8*)&T2[(((tt * 8 + ks) * 4 + quad) * 16 + l15) * 8];

    // U frags direct from L2: feature tiles, 32 per wave, dbuf prefetch
    const int fb0 = wid * 512;
    const unsigned short* Urow = Ub + ((size_t)(fb0 + l15)) * RANK + quad * 8;

#define LDU(dst, ft_)                                                      \
    _Pragma("unroll")                                                      \
    for (int ks = 0; ks < 8; ++ks)                                         \
        dst[ks] = *(const bf16x8*)(Urow + (size_t)(ft_) * 16 * RANK + ks * 32);

#define COMPUTE_STORE(au, ft_) {                                           \
    f32x4 a0 = (f32x4){0.f,0.f,0.f,0.f}, a1 = (f32x4){0.f,0.f,0.f,0.f};    \
    _Pragma("unroll")                                                      \
    for (int ks = 0; ks < 8; ++ks) {                                       \
        a0 = __builtin_amdgcn_mfma_f32_16x16x32_bf16(au[ks], bT[0][ks], a0, 0, 0, 0); \
        a1 = __builtin_amdgcn_mfma_f32_16x16x32_bf16(au[ks], bT[1][ks], a1, 0, 0, 0); \
    }                                                                      \
    int fb = fb0 + (ft_) * 16 + quad * 4;                                  \
    float4 bv = *(const float4*)&bias[fb];                                 \
    float4 v0, v1;                                                         \
    v0.x = a0[0]+bv.x; v0.y = a0[1]+bv.y; v0.z = a0[2]+bv.z; v0.w = a0[3]+bv.w; \
    v1.x = a1[0]+bv.x; v1.y = a1[1]+bv.y; v1.z = a1[2]+bv.z; v1.w = a1[3]+bv.w; \
    *(float4*)&out[(size_t)(m0 + l15) * OUTF + fb]      = v0;              \
    *(float4*)&out[(size_t)(m0 + 16 + l15) * OUTF + fb] = v1;              \
}

    bf16x8 aUa[8], aUb[8];
    LDU(aUa, 0);
    #pragma unroll 1
    for (int ft = 0; ft < 32; ft += 2) {
        LDU(aUb, ft + 1);
        COMPUTE_STORE(aUa, ft);
        if (ft + 2 < 32) { LDU(aUa, ft + 2); }
        COMPUTE_STORE(aUb, ft + 1);
    }
#undef LDU
#undef COMPUTE_STORE
}

extern "C" void kernel_launch(void* const* d_in, const int* in_sizes, int n_in,
                              void* d_out, int out_size, void* d_ws, size_t ws_size,
                              hipStream_t stream) {
    const float* x    = (const float*)d_in[0];
    const float* U    = (const float*)d_in[1];
    const float* V    = (const float*)d_in[2];
    const float* bias = (const float*)d_in[3];
    float* out = (float*)d_out;

    // ws layout: Vb 2MB | Ub 2MB
    unsigned short* Vb = (unsigned short*)d_ws;
    unsigned short* Ub = Vb + (size_t)RANK * INF;

    cvt4<<<(RANK * INF / 4) / 256, 256, 0, stream>>>((const float4*)V, (ushort4*)Vb);
    cvt4<<<(OUTF * RANK / 4) / 256, 256, 0, stream>>>((const float4*)U, (ushort4*)Ub);
    fused<<<TOKENS / BM, 512, 0, stream>>>(x, Vb, Ub, bias, out);
}